// Round 1
// baseline (2309.324 us; speedup 1.0000x reference)
//
#include <hip/hip_runtime.h>
#include <stdint.h>

#define NUM_LABELS 200000
#define HIDDEN 64
#define BATCH 2048
#define LOGITS_SIZE ((size_t)BATCH * (size_t)NUM_LABELS)

typedef __attribute__((ext_vector_type(8))) short short8;
typedef __attribute__((ext_vector_type(16))) float floatx16;
typedef __attribute__((ext_vector_type(4))) int intx4;

static __device__ inline short f2bf(float f) {
  // round-to-nearest-even fp32 -> bf16
  unsigned u = __float_as_uint(f);
  unsigned r = (u + 0x7fffu + ((u >> 16) & 1u)) >> 16;
  return (short)r;
}

// Kernel A: gather embed rows; write fp32 embed to d_out, bf16 A to ws.
// Also zero-init row_sum accumulators (first 2048 threads).
__global__ __launch_bounds__(256) void gather_kernel(
    const int* __restrict__ label, const float* __restrict__ table,
    float* __restrict__ out_embed, short* __restrict__ A_bf16,
    float* __restrict__ row_sum) {
  int idx = blockIdx.x * 256 + threadIdx.x;  // 0..131071
  if (idx < BATCH) row_sum[idx] = 0.0f;
  int i = idx >> 6;
  int j = idx & 63;
  float v = table[(size_t)label[i] * HIDDEN + j];
  out_embed[idx] = v;
  A_bf16[idx] = f2bf(v);
}

// Kernel B: logits GEMM + fused sigmoid + row-wise sum(exp(logit)).
// Block = 256 threads (4 waves). Wave w: rows [by*128 + w*32, +32),
// cols [bx*256, +256) as 8 n-tiles of 32. MFMA 32x32x16 bf16.
__global__ __launch_bounds__(256) void gemm_kernel(
    const short* __restrict__ A,      // [BATCH][64] bf16
    const float* __restrict__ W,      // [NUM_LABELS][64] fp32
    const float* __restrict__ bias,   // [NUM_LABELS]
    float* __restrict__ out,          // [BATCH][NUM_LABELS]
    float* __restrict__ row_sum) {    // [BATCH]
  const int lane = threadIdx.x & 63;
  const int wave = threadIdx.x >> 6;
  const int lm = lane & 31;
  const int half = lane >> 5;
  const int m_base = blockIdx.y * 128 + wave * 32;
  const int n_base0 = blockIdx.x * 256;
  const float LOG2E = 1.44269504f;

  // A fragments: lane holds A[m_base+lm][k = s*16 + half*8 + j], j=0..7
  short8 a[4];
  const short* Arow = A + (size_t)(m_base + lm) * HIDDEN + half * 8;
#pragma unroll
  for (int s = 0; s < 4; ++s)
    a[s] = __builtin_bit_cast(short8, *(const intx4*)(Arow + s * 16));

  float rsum[16];
#pragma unroll
  for (int r = 0; r < 16; ++r) rsum[r] = 0.0f;

  for (int t = 0; t < 8; ++t) {
    const int n_base = n_base0 + t * 32;
    if (n_base >= NUM_LABELS) break;  // uniform tail skip (200000 % 32 == 0)
    const int col = n_base + lm;

    // B fragments: lane holds W[col][k = s*16 + half*8 + j] cast to bf16
    const float4* Wp = (const float4*)(W + (size_t)col * HIDDEN + half * 8);
    floatx16 acc = {};
#pragma unroll
    for (int s = 0; s < 4; ++s) {
      float4 w0 = Wp[4 * s];
      float4 w1 = Wp[4 * s + 1];
      short8 bfr;
      bfr[0] = f2bf(w0.x); bfr[1] = f2bf(w0.y);
      bfr[2] = f2bf(w0.z); bfr[3] = f2bf(w0.w);
      bfr[4] = f2bf(w1.x); bfr[5] = f2bf(w1.y);
      bfr[6] = f2bf(w1.z); bfr[7] = f2bf(w1.w);
      acc = __builtin_amdgcn_mfma_f32_32x32x16_bf16(a[s], bfr, acc, 0, 0, 0);
    }

    const float bv = bias[col];
#pragma unroll
    for (int r = 0; r < 16; ++r) {
      // C/D layout (HW-verified): col = lane&31, row = (r&3)+8*(r>>2)+4*half
      const int row = m_base + (r & 3) + 8 * (r >> 2) + 4 * half;
      float z = acc[r] + bv;
      float sig =
          __builtin_amdgcn_rcpf(1.0f + __builtin_amdgcn_exp2f(-z * LOG2E));
      out[(size_t)row * NUM_LABELS + col] = sig;
      rsum[r] += __builtin_amdgcn_exp2f(sig * LOG2E);
    }
  }

  // Reduce each rsum[r] across the 32 lanes of each half-wave, then one
  // atomicAdd per row. xor masks <= 16 stay within a 32-lane half.
#pragma unroll
  for (int r = 0; r < 16; ++r) {
    float v = rsum[r];
    v += __shfl_xor(v, 16);
    v += __shfl_xor(v, 8);
    v += __shfl_xor(v, 4);
    v += __shfl_xor(v, 2);
    v += __shfl_xor(v, 1);
    if (lm == 0) {
      const int row = m_base + (r & 3) + 8 * (r >> 2) + 4 * half;
      atomicAdd(row_sum + row, v);
    }
  }
}

// Kernel C: exact fp32 logits[i, label[i]] (one wave per row).
__global__ __launch_bounds__(256) void label_logit_kernel(
    const int* __restrict__ label, const float* __restrict__ table,
    const float* __restrict__ W, const float* __restrict__ bias,
    float* __restrict__ label_logit) {
  const int lane = threadIdx.x & 63;
  const int row = blockIdx.x * 4 + (threadIdx.x >> 6);
  const int lbl = label[row];
  float v = table[(size_t)label[row >> 11 == 0 ? row : row] * 0 +
                  (size_t)lbl * HIDDEN + lane] *
            W[(size_t)lbl * HIDDEN + lane];
  v += __shfl_xor(v, 32);
  v += __shfl_xor(v, 16);
  v += __shfl_xor(v, 8);
  v += __shfl_xor(v, 4);
  v += __shfl_xor(v, 2);
  v += __shfl_xor(v, 1);
  if (lane == 0) {
    float z = v + bias[lbl];
    label_logit[row] = __builtin_amdgcn_rcpf(
        1.0f + __builtin_amdgcn_exp2f(-z * 1.44269504f));
  }
}

// Kernel D: loss = -mean(label_logit[i] - log(row_sum[i]))
__global__ __launch_bounds__(256) void loss_kernel(
    const float* __restrict__ row_sum, const float* __restrict__ label_logit,
    float* __restrict__ out_loss) {
  __shared__ float smem[256];
  float acc = 0.0f;
  for (int i = threadIdx.x; i < BATCH; i += 256)
    acc += label_logit[i] - logf(row_sum[i]);
  smem[threadIdx.x] = acc;
  __syncthreads();
  for (int w = 128; w > 0; w >>= 1) {
    if ((int)threadIdx.x < w) smem[threadIdx.x] += smem[threadIdx.x + w];
    __syncthreads();
  }
  if (threadIdx.x == 0) out_loss[0] = -smem[0] / (float)BATCH;
}

extern "C" void kernel_launch(void* const* d_in, const int* in_sizes, int n_in,
                              void* d_out, int out_size, void* d_ws,
                              size_t ws_size, hipStream_t stream) {
  const int* label = (const int*)d_in[0];
  const float* table = (const float*)d_in[1];
  const float* W = (const float*)d_in[2];
  const float* bias = (const float*)d_in[3];

  float* out = (float*)d_out;
  float* out_loss = out + LOGITS_SIZE;
  float* out_embed = out + LOGITS_SIZE + 1;

  char* ws = (char*)d_ws;
  float* row_sum = (float*)ws;                  // 8 KB
  float* label_logit = (float*)(ws + 8192);     // 8 KB
  short* A_bf16 = (short*)(ws + 16384);         // 256 KB

  // A: gather + bf16 cast + row_sum zero-init
  gather_kernel<<<dim3(BATCH * HIDDEN / 256), dim3(256), 0, stream>>>(
      label, table, out_embed, A_bf16, row_sum);

  // B: main GEMM+epilogue. n-blocks cover ceil(6250 tiles / 8).
  const int nblk = (NUM_LABELS / 32 + 7) / 8;  // 782
  gemm_kernel<<<dim3(nblk, BATCH / 128), dim3(256), 0, stream>>>(
      A_bf16, W, bias, out, row_sum);

  // C: exact label logits
  label_logit_kernel<<<dim3(BATCH / 4), dim3(256), 0, stream>>>(
      label, table, W, bias, label_logit);

  // D: finalize loss
  loss_kernel<<<dim3(1), dim3(256), 0, stream>>>(row_sum, label_logit,
                                                 out_loss);
}